// Round 1
// 1975.599 us; speedup vs baseline: 1.0045x; 1.0045x over previous
//
#include <hip/hip_runtime.h>
#include <math.h>

typedef float4 f4;
#define NW 248
#define NB 64
#define NPH (NW * 8)   // 1984 L0-steps; loop runs t = 0..NPH inclusive (skewed L1)

__device__ __forceinline__ float sigm(float x)   { return __builtin_amdgcn_rcpf(1.0f + __expf(-x)); }
__device__ __forceinline__ float tanh_f(float x) { return 2.0f * __builtin_amdgcn_rcpf(1.0f + __expf(-2.0f * x)) - 1.0f; }

// 8 NAMED float4 registers loaded from P
#define L8(V,P) \
  f4 V##0=(P)[0],V##1=(P)[1],V##2=(P)[2],V##3=(P)[3],V##4=(P)[4],V##5=(P)[5],V##6=(P)[6],V##7=(P)[7];

// Opacity launder: asm outputs are NOT rematerializable -> RA must keep in VGPRs.
#define OPQ1(X) asm volatile("" : "+v"(X));
#define OPQ4(V) OPQ1(V.x) OPQ1(V.y) OPQ1(V.z) OPQ1(V.w)
#define OPQ8(V) OPQ4(V##0) OPQ4(V##1) OPQ4(V##2) OPQ4(V##3) OPQ4(V##4) OPQ4(V##5) OPQ4(V##6) OPQ4(V##7)

#define FMA1(acc,W,H) { f4 h_=(H); acc=fmaf((W).x,h_.x,acc); acc=fmaf((W).y,h_.y,acc); \
                        acc=fmaf((W).z,h_.z,acc); acc=fmaf((W).w,h_.w,acc); }

// 32-FMA dot over 8 named float4 weights vs LDS float4* HB, 4 rotating accumulators
#define DOT8(q0,q1,q2,q3,V,HB) \
  FMA1(q0,V##0,(HB)[0]) FMA1(q1,V##1,(HB)[1]) FMA1(q2,V##2,(HB)[2]) FMA1(q3,V##3,(HB)[3]) \
  FMA1(q0,V##4,(HB)[4]) FMA1(q1,V##5,(HB)[5]) FMA1(q2,V##6,(HB)[6]) FMA1(q3,V##7,(HB)[7])

__global__ __launch_bounds__(512) __attribute__((amdgpu_waves_per_eu(2)))
void or_lstm_skew(const float* __restrict__ traj,
                  const float* __restrict__ Wih0, const float* __restrict__ Whh0,
                  const float* __restrict__ bih0, const float* __restrict__ bhh0,
                  const float* __restrict__ Wih1, const float* __restrict__ Whh1,
                  const float* __restrict__ bih1, const float* __restrict__ bhh1,
                  const float* __restrict__ Wlin, const float* __restrict__ blin,
                  float* __restrict__ out)
{
    const int row  = blockIdx.x;
    const int tid  = threadIdx.x;       // = ((j*4)+g)*2 + half
    const int half = tid & 1;           // K-half 0..1
    const int rr   = tid >> 1;          // 0..255
    const int j    = rr >> 2;           // h index 0..63
    const int g    = rr & 3;            // gate 0=i,1=f,2=g(tanh),3=o
    const int r    = g * 64 + j;        // weight-matrix row
    const int ko   = half * 32;         // K offset

    __shared__ __align__(16) float trajS[256 * 4];
    __shared__ __align__(16) float X0[2][64];   // double-buffered h, layer 0
    __shared__ __align__(16) float X1[2][64];   // double-buffered h, layer 1
    __shared__ __align__(16) float Zb[64];      // permanent zero vector (window-start h)
    __shared__ float outr[8][2];                // ring of last 8 predictions

    if (tid < 256)
        ((f4*)trajS)[tid] = ((const f4*)(traj + (size_t)row * 256 * 4))[tid];
    if (tid < 64) Zb[tid] = 0.f;

    // ---- per-thread half-rows of weights -> registers, laundered opaque ----
    const f4* pA = (const f4*)(Whh0 + r * 64 + ko);
    const f4* pB = (const f4*)(Wih1 + r * 64 + ko);
    const f4* pC = (const f4*)(Whh1 + r * 64 + ko);
    L8(A, pA)
    L8(Bv, pB)
    L8(Cv, pC)
    OPQ8(A)
    OPQ8(Bv)
    OPQ8(Cv)
    float wiA = Wih0[r * 4 + 2 * half];
    float wiB = Wih0[r * 4 + 2 * half + 1];
    float bb0 = half ? 0.f : (bih0[r] + bhh0[r]);
    float bb1 = half ? 0.f : (bih1[r] + bhh1[r]);
    OPQ1(wiA) OPQ1(wiB) OPQ1(bb0) OPQ1(bb1)
    float wl = 0.f;
    if (tid < 128) wl = Wlin[tid];      // wave0: Wlin row0, wave1: row1
    const float bl0 = blin[0], bl1 = blin[1];

    const int lane  = tid & 63;
    const int qbase = lane & ~7;        // first lane of this j's 8-lane group
    const int gsel  = qbase + half;     // gate G of own half at lane gsel + 2G

    float cc0 = 0.f, cc1 = 0.f, h0v = 0.f, h1v = 0.f;

    __syncthreads();

    // Skewed pipeline: phase t computes L0(step t) || L1(step t-1).
    // Both only read state written in phase t-1 -> independent chains, ONE barrier/phase.
    for (int t = 0; t <= NPH; ++t) {
        const int rb = (t & 1) ^ 1, wb = t & 1;
        const int s  = t & 7;           // L0 step-in-window  (L1's step-in-window == s-1 mod 8)
        const int w  = t >> 3;          // L0 window
        const bool doL0 = (t < NPH);

        // ---- L0 input x(w, s) ----  (at t==NPH this is harmless dummy work: w=248, tc<=248)
        float x0, x1, x2, x3;
        if (w == 0) {
            x0 = trajS[s*4+0]; x1 = trajS[s*4+1]; x2 = trajS[s*4+2]; x3 = trajS[s*4+3];
        } else if (w < 8) {
            if (s < 8 - w) {
                const int tt = w + s;
                x0 = trajS[tt*4+0]; x1 = trajS[tt*4+1]; x2 = trajS[tt*4+2]; x3 = trajS[tt*4+3];
            } else {
                const int tc = 2*w + s - 1;
                const int jo = (w + s - 8) & 7;
                x0 = trajS[tc*4+0]; x1 = trajS[tc*4+1];
                x2 = outr[jo][0];   x3 = outr[jo][1];
            }
        } else {
            const int tc = w + s;
            const int jo = (w + s) & 7;
            x0 = trajS[tc*4+0]; x1 = trajS[tc*4+1];
            x2 = outr[jo][0];   x3 = outr[jo][1];
        }
        const float xa = half ? x2 : x0;
        const float xb = half ? x3 : x1;

        // ---- both dots, branchless via zero-buffer select (keeps ONE basic block) ----
        // L0(s==0) has h0=0; L1(step t-1, window-start when s==1) has h1=0.
        const f4* H0  = (const f4*)((s == 0)           ? &Zb[ko] : &X0[rb][ko]);
        const f4* H0b = (const f4*)(&X0[rb][ko]);                    // L1 input h0(t-1): always valid
        const f4* H1  = (const f4*)((s == 1 || t == 0) ? &Zb[ko] : &X1[rb][ko]);

        float q0 = fmaf(wiA, xa, fmaf(wiB, xb, bb0)), q1 = 0.f, q2 = 0.f, q3 = 0.f;
        float p0 = bb1,                               p1 = 0.f, p2 = 0.f, p3 = 0.f;
        DOT8(q0, q1, q2, q3, A,  H0)     // L0: Whh0 . h0(t-1)
        DOT8(p0, p1, p2, p3, Bv, H0b)    // L1: Wih1 . h0(t-1)
        DOT8(p0, p1, p2, p3, Cv, H1)     // L1: Whh1 . h1(t-2)

        // ---- finish both layers, interleaved (independent latency chains) ----
        float acc0 = (q0 + q2) + (q1 + q3);
        float acc1 = (p0 + p2) + (p1 + p3);
        acc0 += __shfl_xor(acc0, 1, 64);             // combine K-halves
        acc1 += __shfl_xor(acc1, 1, 64);
        float a0 = (g == 2) ? tanh_f(acc0) : sigm(acc0);
        float a1 = (g == 2) ? tanh_f(acc1) : sigm(acc1);
        float ai0 = __shfl(a0, gsel + 0, 64);
        float af0 = __shfl(a0, gsel + 2, 64);
        float ag0 = __shfl(a0, gsel + 4, 64);
        float ao0 = __shfl(a0, gsel + 6, 64);
        float ai1 = __shfl(a1, gsel + 0, 64);
        float af1 = __shfl(a1, gsel + 2, 64);
        float ag1 = __shfl(a1, gsel + 4, 64);
        float ao1 = __shfl(a1, gsel + 6, 64);

        cc0 = doL0 ? ((s == 0) ? (ai0 * ag0) : fmaf(af0, cc0, ai0 * ag0)) : cc0;
        const float nh0 = ao0 * tanh_f(cc0);
        h0v = doL0 ? nh0 : h0v;
        if (doL0 && g == 0 && half == 0) X0[wb][j] = nh0;

        cc1 = (s == 1) ? (ai1 * ag1) : fmaf(af1, cc1, ai1 * ag1);   // t==0 garbage is flushed at t==1
        h1v = ao1 * tanh_f(cc1);
        if (g == 0 && half == 0) X1[wb][j] = h1v;

        // ---- epilogue for window w1 = t/8 - 1 (h1(w1,7) landed in X1[0] last phase) ----
        // waves 0/1 each reduce one output component; slot (w1&7) never collides with
        // this phase's x-reads (those hit slots (w+s)&7 = (w1+2)&7 or earlier windows).
        if ((s == 1) && (t > 8) && (tid < 128)) {
            const int w1 = (t >> 3) - 1;
            const int l  = tid & 63, wv = tid >> 6;
            const float hv = X1[0][l];
            float p = wl * hv;
#pragma unroll
            for (int off = 32; off > 0; off >>= 1) p += __shfl_down(p, off);
            if (l == 0) {
                const float prev = (w1 == 0) ? trajS[7*4 + 2 + wv] : outr[(w1 - 1) & 7][wv];
                const float o = prev + p + (wv ? bl1 : bl0);
                outr[w1 & 7][wv] = o;
                out[((size_t)row * NW + w1) * 2 + wv] = o;
            }
        }
        __syncthreads();                 // the ONE barrier per phase
    }

    // ---- final epilogue: window NW-1 (h1 in X1[0], wb of phase NPH is 0) ----
    if (tid < 128) {
        const int l = tid & 63, wv = tid >> 6;
        const float hv = X1[0][l];
        float p = wl * hv;
#pragma unroll
        for (int off = 32; off > 0; off >>= 1) p += __shfl_down(p, off);
        if (l == 0) {
            const float prev = outr[(NW - 2) & 7][wv];
            const float o = prev + p + (wv ? bl1 : bl0);
            out[((size_t)row * NW + (NW - 1)) * 2 + wv] = o;
        }
    }

    // ---- final hidden/cell state ----
    if (g == 0 && half == 0) {
        float* hn = out + (size_t)NB * NW * 2;
        float* cn = hn + 2 * NB * 64;
        hn[(0 * NB + row) * 64 + j] = h0v;
        hn[(1 * NB + row) * 64 + j] = h1v;
        cn[(0 * NB + row) * 64 + j] = cc0;
        cn[(1 * NB + row) * 64 + j] = cc1;
    }
}

extern "C" void kernel_launch(void* const* d_in, const int* in_sizes, int n_in,
                              void* d_out, int out_size, void* d_ws, size_t ws_size,
                              hipStream_t stream) {
    const float* traj = (const float*)d_in[0];
    const float* Wih0 = (const float*)d_in[1];
    const float* Whh0 = (const float*)d_in[2];
    const float* bih0 = (const float*)d_in[3];
    const float* bhh0 = (const float*)d_in[4];
    const float* Wih1 = (const float*)d_in[5];
    const float* Whh1 = (const float*)d_in[6];
    const float* bih1 = (const float*)d_in[7];
    const float* bhh1 = (const float*)d_in[8];
    const float* Wlin = (const float*)d_in[9];
    const float* blin = (const float*)d_in[10];
    float* out = (float*)d_out;

    or_lstm_skew<<<dim3(NB), dim3(512), 0, stream>>>(
        traj, Wih0, Whh0, bih0, bhh0, Wih1, Whh1, bih1, bhh1, Wlin, blin, out);
}

// Round 2
// 1634.012 us; speedup vs baseline: 1.2145x; 1.2090x over previous
//
#include <hip/hip_runtime.h>
#include <math.h>

typedef float4 f4;
#define NW 248
#define NB 64
#define NPH (NW * 8)   // 1984 L0-steps; loop runs t = 0..NPH inclusive (skewed L1)

__device__ __forceinline__ float sigm(float x)   { return __builtin_amdgcn_rcpf(1.0f + __expf(-x)); }
__device__ __forceinline__ float tanh_f(float x) { return 2.0f * __builtin_amdgcn_rcpf(1.0f + __expf(-2.0f * x)) - 1.0f; }

// Sum over an aligned 8-lane group (lane bits 0..2).
// xor1/xor2 via DPP quad_perm (pure VALU), xor4 via ds_swizzle (1 LDS-pipe op).
__device__ __forceinline__ float red8(float v) {
    v += __int_as_float(__builtin_amdgcn_update_dpp(0, __float_as_int(v), 0xB1, 0xF, 0xF, true)); // [1,0,3,2]
    v += __int_as_float(__builtin_amdgcn_update_dpp(0, __float_as_int(v), 0x4E, 0xF, 0xF, true)); // [2,3,0,1]
    v += __int_as_float(__builtin_amdgcn_ds_swizzle(__float_as_int(v), 0x101F));                  // lane^4
    return v;
}

// Opacity launder: keep weight registers pinned in VGPRs.
#define OPQ1(X) asm volatile("" : "+v"(X));
#define OPQ4(V) OPQ1(V.x) OPQ1(V.y) OPQ1(V.z) OPQ1(V.w)

#define FMA4(acc,W,H) { acc=fmaf((W).x,(H).x,acc); acc=fmaf((W).y,(H).y,acc); \
                        acc=fmaf((W).z,(H).z,acc); acc=fmaf((W).w,(H).w,acc); }

// Per-gate weight slices: M##G##a/b = rows g*64+j, cols idx*8..idx*8+7 (2 f4 each)
#define LDW(M, SRC) \
  f4 M##0a = *(const f4*)((SRC) + 0*4096 + wo), M##0b = *(const f4*)((SRC) + 0*4096 + wo + 4); \
  f4 M##1a = *(const f4*)((SRC) + 1*4096 + wo), M##1b = *(const f4*)((SRC) + 1*4096 + wo + 4); \
  f4 M##2a = *(const f4*)((SRC) + 2*4096 + wo), M##2b = *(const f4*)((SRC) + 2*4096 + wo + 4); \
  f4 M##3a = *(const f4*)((SRC) + 3*4096 + wo), M##3b = *(const f4*)((SRC) + 3*4096 + wo + 4);

__global__ __launch_bounds__(512)
void or_lstm_slice(const float* __restrict__ traj,
                   const float* __restrict__ Wih0, const float* __restrict__ Whh0,
                   const float* __restrict__ bih0, const float* __restrict__ bhh0,
                   const float* __restrict__ Wih1, const float* __restrict__ Whh1,
                   const float* __restrict__ bih1, const float* __restrict__ bhh1,
                   const float* __restrict__ Wlin, const float* __restrict__ blin,
                   float* __restrict__ out)
{
    const int row = blockIdx.x;
    const int tid = threadIdx.x;      // = j*8 + idx
    const int j   = tid >> 3;         // h index 0..63
    const int idx = tid & 7;          // K-slice 0..7 (8 floats each)

    __shared__ __align__(16) float trajS[256 * 4];
    __shared__ __align__(16) float X0[2][64];   // double-buffered h, layer 0
    __shared__ __align__(16) float X1[2][64];   // double-buffered h, layer 1
    __shared__ float outr[8][2];                // ring of last 8 predictions

    if (tid < 256)
        ((f4*)trajS)[tid] = ((const f4*)(traj + (size_t)row * 256 * 4))[tid];

    // ---- per-thread weight slices -> registers, laundered opaque ----
    const int wo = j * 64 + idx * 8;            // (g*64+j)*64 + idx*8 = g*4096 + wo
    LDW(A, Whh0)   // layer0 recurrent
    LDW(B, Wih1)   // layer1 input (h0)
    LDW(C, Whh1)   // layer1 recurrent
    OPQ4(A0a) OPQ4(A0b) OPQ4(A1a) OPQ4(A1b) OPQ4(A2a) OPQ4(A2b) OPQ4(A3a) OPQ4(A3b)
    OPQ4(B0a) OPQ4(B0b) OPQ4(B1a) OPQ4(B1b) OPQ4(B2a) OPQ4(B2b) OPQ4(B3a) OPQ4(B3b)
    OPQ4(C0a) OPQ4(C0b) OPQ4(C1a) OPQ4(C1b) OPQ4(C2a) OPQ4(C2b) OPQ4(C3a) OPQ4(C3b)

    // x-columns distributed over idx 0..3; idx>=4 contribute 0 via zeroed weight
    const int r4 = j * 4 + (idx & 3);
    float wx0 = (idx < 4) ? Wih0[0*256 + r4] : 0.f;
    float wx1 = (idx < 4) ? Wih0[1*256 + r4] : 0.f;
    float wx2 = (idx < 4) ? Wih0[2*256 + r4] : 0.f;
    float wx3 = (idx < 4) ? Wih0[3*256 + r4] : 0.f;
    // biases applied only at idx==0
    float bb0s0 = (idx == 0) ? (bih0[0*64+j] + bhh0[0*64+j]) : 0.f;
    float bb0s1 = (idx == 0) ? (bih0[1*64+j] + bhh0[1*64+j]) : 0.f;
    float bb0s2 = (idx == 0) ? (bih0[2*64+j] + bhh0[2*64+j]) : 0.f;
    float bb0s3 = (idx == 0) ? (bih0[3*64+j] + bhh0[3*64+j]) : 0.f;
    float bb1s0 = (idx == 0) ? (bih1[0*64+j] + bhh1[0*64+j]) : 0.f;
    float bb1s1 = (idx == 0) ? (bih1[1*64+j] + bhh1[1*64+j]) : 0.f;
    float bb1s2 = (idx == 0) ? (bih1[2*64+j] + bhh1[2*64+j]) : 0.f;
    float bb1s3 = (idx == 0) ? (bih1[3*64+j] + bhh1[3*64+j]) : 0.f;
    OPQ1(wx0) OPQ1(wx1) OPQ1(wx2) OPQ1(wx3)
    OPQ1(bb0s0) OPQ1(bb0s1) OPQ1(bb0s2) OPQ1(bb0s3)
    OPQ1(bb1s0) OPQ1(bb1s1) OPQ1(bb1s2) OPQ1(bb1s3)

    float wl = 0.f;
    if (tid < 128) wl = Wlin[tid];    // wave0: Wlin row0, wave1: row1
    const float bl0 = blin[0], bl1 = blin[1];

    const bool lo = (idx < 4);        // lanes idx<4 own layer0's cell, idx>=4 layer1's

    float cc0 = 0.f, cc1 = 0.f, h0v = 0.f, h1v = 0.f;

    __syncthreads();

    // Skewed pipeline: phase t computes L0(step t) || L1(step t-1).
    for (int t = 0; t <= NPH; ++t) {
        const int rb = (t & 1) ^ 1, wb = t & 1;
        const int s  = t & 7;
        const int w  = t >> 3;
        const bool doL0 = (t < NPH);

        // ---- L0 input x(w, s) ---- (verbatim sourcing from verified kernel)
        float x0, x1, x2, x3;
        if (w == 0) {
            x0 = trajS[s*4+0]; x1 = trajS[s*4+1]; x2 = trajS[s*4+2]; x3 = trajS[s*4+3];
        } else if (w < 8) {
            if (s < 8 - w) {
                const int tt = w + s;
                x0 = trajS[tt*4+0]; x1 = trajS[tt*4+1]; x2 = trajS[tt*4+2]; x3 = trajS[tt*4+3];
            } else {
                const int tc = 2*w + s - 1;
                const int jo = (w + s - 8) & 7;
                x0 = trajS[tc*4+0]; x1 = trajS[tc*4+1];
                x2 = outr[jo][0];   x3 = outr[jo][1];
            }
        } else {
            const int tc = w + s;
            const int jo = (w + s) & 7;
            x0 = trajS[tc*4+0]; x1 = trajS[tc*4+1];
            x2 = outr[jo][0];   x3 = outr[jo][1];
        }
        const float xsel = (idx & 2) ? ((idx & 1) ? x3 : x2) : ((idx & 1) ? x1 : x0);

        // ---- h-state slices (each lane reads ONLY its 8-float K-slice) ----
        const f4* H0p = (const f4*)(&X0[rb][idx * 8]);
        const f4* H1p = (const f4*)(&X1[rb][idx * 8]);
        f4 h0a = H0p[0], h0b = H0p[1];          // h0(t-1): L0 (unless s==0) and L1 input

        // ---- L0 gate partials ----
        float q0a = fmaf(wx0, xsel, bb0s0), q0b = 0.f;
        float q1a = fmaf(wx1, xsel, bb0s1), q1b = 0.f;
        float q2a = fmaf(wx2, xsel, bb0s2), q2b = 0.f;
        float q3a = fmaf(wx3, xsel, bb0s3), q3b = 0.f;
        if (s != 0) {                            // uniform: window start has h0 = 0
            FMA4(q0a, A0a, h0a) FMA4(q0b, A0b, h0b)
            FMA4(q1a, A1a, h0a) FMA4(q1b, A1b, h0b)
            FMA4(q2a, A2a, h0a) FMA4(q2b, A2b, h0b)
            FMA4(q3a, A3a, h0a) FMA4(q3b, A3b, h0b)
        }

        // ---- L1 gate partials (step t-1): Wih1.h0(t-1) + Whh1.h1(t-2) ----
        float p0a = bb1s0, p0b = 0.f;
        float p1a = bb1s1, p1b = 0.f;
        float p2a = bb1s2, p2b = 0.f;
        float p3a = bb1s3, p3b = 0.f;
        FMA4(p0a, B0a, h0a) FMA4(p0b, B0b, h0b)
        FMA4(p1a, B1a, h0a) FMA4(p1b, B1b, h0b)
        FMA4(p2a, B2a, h0a) FMA4(p2b, B2b, h0b)
        FMA4(p3a, B3a, h0a) FMA4(p3b, B3b, h0b)
        if (!(s == 1 || t == 0)) {               // uniform: L1 window start has h1 = 0
            f4 h1a = H1p[0], h1b = H1p[1];
            FMA4(p0a, C0a, h1a) FMA4(p0b, C0b, h1b)
            FMA4(p1a, C1a, h1a) FMA4(p1b, C1b, h1b)
            FMA4(p2a, C2a, h1a) FMA4(p2b, C2b, h1b)
            FMA4(p3a, C3a, h1a) FMA4(p3b, C3b, h1b)
        }

        // ---- reductions: all 8 idx lanes end with full sums for all 8 gates ----
        const float y0i = red8(q0a + q0b);
        const float y0f = red8(q1a + q1b);
        const float y0g = red8(q2a + q2b);
        const float y0o = red8(q3a + q3b);
        const float y1i = red8(p0a + p0b);
        const float y1f = red8(p1a + p1b);
        const float y1g = red8(p2a + p2b);
        const float y1o = red8(p3a + p3b);

        // ---- activations: idx<4 lanes run layer0's cell, idx>=4 layer1's ----
        const float yi = lo ? y0i : y1i;
        const float yf = lo ? y0f : y1f;
        const float yg = lo ? y0g : y1g;
        const float yo = lo ? y0o : y1o;
        const float ia = sigm(yi), fa = sigm(yf), ga = tanh_f(yg), oa = sigm(yo);
        const float ig = ia * ga;

        cc0 = doL0 ? ((s == 0) ? ig : fmaf(fa, cc0, ig)) : cc0;   // valid in lo lanes
        cc1 = (s == 1) ? ig : fmaf(fa, cc1, ig);                  // valid in hi lanes
        const float th   = tanh_f(lo ? cc0 : cc1);
        const float hnew = oa * th;
        h0v = (doL0 && lo) ? hnew : h0v;
        h1v = lo ? h1v : hnew;

        if (doL0 && idx == 0) X0[wb][j] = hnew;   // layer0 h
        if (idx == 4)         X1[wb][j] = hnew;   // layer1 h

        // ---- epilogue for window w1 = t/8 - 1 (h1(w1,7) landed in X1[0] last phase) ----
        if ((s == 1) && (t > 8) && (tid < 128)) {
            const int w1 = (t >> 3) - 1;
            const int l  = tid & 63, wv = tid >> 6;
            const float hv = X1[0][l];
            float p = wl * hv;
#pragma unroll
            for (int off = 32; off > 0; off >>= 1) p += __shfl_down(p, off);
            if (l == 0) {
                const float prev = (w1 == 0) ? trajS[7*4 + 2 + wv] : outr[(w1 - 1) & 7][wv];
                const float o = prev + p + (wv ? bl1 : bl0);
                outr[w1 & 7][wv] = o;
                out[((size_t)row * NW + w1) * 2 + wv] = o;
            }
        }
        __syncthreads();                 // the ONE barrier per phase
    }

    // ---- final epilogue: window NW-1 (h1 in X1[0]) ----
    if (tid < 128) {
        const int l = tid & 63, wv = tid >> 6;
        const float hv = X1[0][l];
        float p = wl * hv;
#pragma unroll
        for (int off = 32; off > 0; off >>= 1) p += __shfl_down(p, off);
        if (l == 0) {
            const float prev = outr[(NW - 2) & 7][wv];
            const float o = prev + p + (wv ? bl1 : bl0);
            out[((size_t)row * NW + (NW - 1)) * 2 + wv] = o;
        }
    }

    // ---- final hidden/cell state ----
    {
        float* hn = out + (size_t)NB * NW * 2;
        float* cn = hn + 2 * NB * 64;
        if (idx == 0) {                       // lo lanes own layer0 state
            hn[(0 * NB + row) * 64 + j] = h0v;
            cn[(0 * NB + row) * 64 + j] = cc0;
        }
        if (idx == 4) {                       // hi lanes own layer1 state
            hn[(1 * NB + row) * 64 + j] = h1v;
            cn[(1 * NB + row) * 64 + j] = cc1;
        }
    }
}

extern "C" void kernel_launch(void* const* d_in, const int* in_sizes, int n_in,
                              void* d_out, int out_size, void* d_ws, size_t ws_size,
                              hipStream_t stream) {
    const float* traj = (const float*)d_in[0];
    const float* Wih0 = (const float*)d_in[1];
    const float* Whh0 = (const float*)d_in[2];
    const float* bih0 = (const float*)d_in[3];
    const float* bhh0 = (const float*)d_in[4];
    const float* Wih1 = (const float*)d_in[5];
    const float* Whh1 = (const float*)d_in[6];
    const float* bih1 = (const float*)d_in[7];
    const float* bhh1 = (const float*)d_in[8];
    const float* Wlin = (const float*)d_in[9];
    const float* blin = (const float*)d_in[10];
    float* out = (float*)d_out;

    or_lstm_slice<<<dim3(NB), dim3(512), 0, stream>>>(
        traj, Wih0, Whh0, bih0, bhh0, Wih1, Whh1, bih1, bhh1, Wlin, blin, out);
}

// Round 3
// 1416.134 us; speedup vs baseline: 1.4014x; 1.1539x over previous
//
#include <hip/hip_runtime.h>
#include <math.h>

typedef float4 f4;
#define NW 248
#define NB 64
#define NPH (NW * 8)   // 1984 L0-steps; loop runs t = 0..NPH inclusive (skewed L1)

__device__ __forceinline__ float tanh_f(float x) { return 2.0f * __builtin_amdgcn_rcpf(1.0f + __expf(-2.0f * x)) - 1.0f; }

// Single-op cross-lane via DPP (no LDS pipe).
template<int CTRL>
__device__ __forceinline__ float dppf(float v) {
    return __int_as_float(__builtin_amdgcn_update_dpp(0, __float_as_int(v), CTRL, 0xF, 0xF, true));
}
#define XOR1 0xB1   // quad_perm [1,0,3,2]
#define XOR2 0x4E   // quad_perm [2,3,0,1]
#define MIR7 0x141  // ROW_HALF_MIRROR: lane i -> 7-i within 8  (== xor 7)
#define BC0  0x00   // quad_perm [0,0,0,0]
#define BC1  0x55
#define BC2  0xAA
#define BC3  0xFF

// Opacity launder: keep weight registers pinned in VGPRs.
#define OPQ1(X) asm volatile("" : "+v"(X));
#define OPQ4(V) OPQ1(V.x) OPQ1(V.y) OPQ1(V.z) OPQ1(V.w)

#define FMA4(acc,W,H) { acc=fmaf((W).x,(H).x,acc); acc=fmaf((W).y,(H).y,acc); \
                        acc=fmaf((W).z,(H).z,acc); acc=fmaf((W).w,(H).w,acc); }

__global__ __launch_bounds__(512)
void or_lstm_dpp(const float* __restrict__ traj,
                 const float* __restrict__ Wih0, const float* __restrict__ Whh0,
                 const float* __restrict__ bih0, const float* __restrict__ bhh0,
                 const float* __restrict__ Wih1, const float* __restrict__ Whh1,
                 const float* __restrict__ bih1, const float* __restrict__ bhh1,
                 const float* __restrict__ Wlin, const float* __restrict__ blin,
                 float* __restrict__ out)
{
    const int row = blockIdx.x;
    const int tid = threadIdx.x;      // = j*8 + idx
    const int j   = tid >> 3;         // h index 0..63
    const int idx = tid & 7;          // K-slice 0..7 (8 floats each)
    const int q2  = idx & 3;          // position within DPP quad

    __shared__ __align__(16) float trajS[256 * 4];
    __shared__ __align__(16) float X0[2][64];   // double-buffered h, layer 0
    __shared__ __align__(16) float X1[2][64];   // double-buffered h, layer 1
    __shared__ float outr[8][2];                // ring of last 8 predictions

    if (tid < 256)
        ((f4*)trajS)[tid] = ((const f4*)(traj + (size_t)row * 256 * 4))[tid];

    // ---- gate-permuted weight slices: slot m holds gate v = m ^ q2 ----
    // bit2(v) == bit2(m): slots 0-3 are ALWAYS layer0, 4-7 ALWAYS layer1.
    const int jo = j * 64 + idx * 8;
    const int v0 = 0 ^ q2, v1 = 1 ^ q2, v2 = 2 ^ q2, v3 = 3 ^ q2;
    // layer0 recurrent (Whh0), slots 0-3
    f4 W0a = *(const f4*)(Whh0 + v0*4096 + jo), W0b = *(const f4*)(Whh0 + v0*4096 + jo + 4);
    f4 W1a = *(const f4*)(Whh0 + v1*4096 + jo), W1b = *(const f4*)(Whh0 + v1*4096 + jo + 4);
    f4 W2a = *(const f4*)(Whh0 + v2*4096 + jo), W2b = *(const f4*)(Whh0 + v2*4096 + jo + 4);
    f4 W3a = *(const f4*)(Whh0 + v3*4096 + jo), W3b = *(const f4*)(Whh0 + v3*4096 + jo + 4);
    // layer1 input (Wih1) + recurrent (Whh1), slots 4-7 (gate v_{m-4})
    f4 U4a = *(const f4*)(Wih1 + v0*4096 + jo), U4b = *(const f4*)(Wih1 + v0*4096 + jo + 4);
    f4 U5a = *(const f4*)(Wih1 + v1*4096 + jo), U5b = *(const f4*)(Wih1 + v1*4096 + jo + 4);
    f4 U6a = *(const f4*)(Wih1 + v2*4096 + jo), U6b = *(const f4*)(Wih1 + v2*4096 + jo + 4);
    f4 U7a = *(const f4*)(Wih1 + v3*4096 + jo), U7b = *(const f4*)(Wih1 + v3*4096 + jo + 4);
    f4 V4a = *(const f4*)(Whh1 + v0*4096 + jo), V4b = *(const f4*)(Whh1 + v0*4096 + jo + 4);
    f4 V5a = *(const f4*)(Whh1 + v1*4096 + jo), V5b = *(const f4*)(Whh1 + v1*4096 + jo + 4);
    f4 V6a = *(const f4*)(Whh1 + v2*4096 + jo), V6b = *(const f4*)(Whh1 + v2*4096 + jo + 4);
    f4 V7a = *(const f4*)(Whh1 + v3*4096 + jo), V7b = *(const f4*)(Whh1 + v3*4096 + jo + 4);
    OPQ4(W0a) OPQ4(W0b) OPQ4(W1a) OPQ4(W1b) OPQ4(W2a) OPQ4(W2b) OPQ4(W3a) OPQ4(W3b)
    OPQ4(U4a) OPQ4(U4b) OPQ4(U5a) OPQ4(U5b) OPQ4(U6a) OPQ4(U6b) OPQ4(U7a) OPQ4(U7b)
    OPQ4(V4a) OPQ4(V4b) OPQ4(V5a) OPQ4(V5b) OPQ4(V6a) OPQ4(V6b) OPQ4(V7a) OPQ4(V7b)

    // x-weights: lane idx<4 contributes input column idx to L0 gates (slot m: gate v_m)
    float wx0 = (idx < 4) ? Wih0[v0*256 + j*4 + q2] : 0.f;
    float wx1 = (idx < 4) ? Wih0[v1*256 + j*4 + q2] : 0.f;
    float wx2 = (idx < 4) ? Wih0[v2*256 + j*4 + q2] : 0.f;
    float wx3 = (idx < 4) ? Wih0[v3*256 + j*4 + q2] : 0.f;
    // biases: added once per value, at idx==0 (where v_m == m)
    float bb0 = (idx == 0) ? (bih0[0*64+j] + bhh0[0*64+j]) : 0.f;
    float bb1 = (idx == 0) ? (bih0[1*64+j] + bhh0[1*64+j]) : 0.f;
    float bb2 = (idx == 0) ? (bih0[2*64+j] + bhh0[2*64+j]) : 0.f;
    float bb3 = (idx == 0) ? (bih0[3*64+j] + bhh0[3*64+j]) : 0.f;
    float bb4 = (idx == 0) ? (bih1[0*64+j] + bhh1[0*64+j]) : 0.f;
    float bb5 = (idx == 0) ? (bih1[1*64+j] + bhh1[1*64+j]) : 0.f;
    float bb6 = (idx == 0) ? (bih1[2*64+j] + bhh1[2*64+j]) : 0.f;
    float bb7 = (idx == 0) ? (bih1[3*64+j] + bhh1[3*64+j]) : 0.f;
    OPQ1(wx0) OPQ1(wx1) OPQ1(wx2) OPQ1(wx3)
    OPQ1(bb0) OPQ1(bb1) OPQ1(bb2) OPQ1(bb3)
    OPQ1(bb4) OPQ1(bb5) OPQ1(bb6) OPQ1(bb7)

    // unified activation coefs: gate q2==2 is tanh, others sigmoid
    // a = s2 * rcp(1 + exp(ka*y)) + s3 ; sigm: (-1,1,0)  tanh: (-2,2,-1)
    const float kae = (q2 == 2) ? -2.f : -1.f;
    const float fs2 = (q2 == 2) ?  2.f :  1.f;
    const float fs3 = (q2 == 2) ? -1.f :  0.f;

    float wl = 0.f;
    if (tid < 128) wl = Wlin[tid];    // wave0: Wlin row0, wave1: row1
    const float bl0 = blin[0], bl1 = blin[1];

    const bool lolane = (idx < 4);    // quad0 runs layer0's cell, quad1 layer1's
    float cc = 0.f, hv = 0.f;         // per-quad cell/h state (L0 in quad0, L1 in quad1)

    __syncthreads();

    // Skewed pipeline: phase t computes L0(step t) || L1(step t-1).
    for (int t = 0; t <= NPH; ++t) {
        const int rb = (t & 1) ^ 1, wb = t & 1;
        const int s  = t & 7;
        const int w  = t >> 3;
        const bool doL0 = (t < NPH);

        // ---- L0 input x(w, s) ---- (verbatim sourcing from verified kernel)
        float x0, x1, x2, x3;
        if (w == 0) {
            x0 = trajS[s*4+0]; x1 = trajS[s*4+1]; x2 = trajS[s*4+2]; x3 = trajS[s*4+3];
        } else if (w < 8) {
            if (s < 8 - w) {
                const int tt = w + s;
                x0 = trajS[tt*4+0]; x1 = trajS[tt*4+1]; x2 = trajS[tt*4+2]; x3 = trajS[tt*4+3];
            } else {
                const int tc = 2*w + s - 1;
                const int jo2 = (w + s - 8) & 7;
                x0 = trajS[tc*4+0]; x1 = trajS[tc*4+1];
                x2 = outr[jo2][0];  x3 = outr[jo2][1];
            }
        } else {
            const int tc = w + s;
            const int jo2 = (w + s) & 7;
            x0 = trajS[tc*4+0]; x1 = trajS[tc*4+1];
            x2 = outr[jo2][0];  x3 = outr[jo2][1];
        }
        const float xsel = (q2 & 2) ? ((q2 & 1) ? x3 : x2) : ((q2 & 1) ? x1 : x0);

        // ---- h-state slices ----
        const f4* H0p = (const f4*)(&X0[rb][idx * 8]);
        const f4* H1p = (const f4*)(&X1[rb][idx * 8]);
        f4 h0a = H0p[0], h0b = H0p[1];

        // ---- gate partials (slot m = gate m^q2; L0 slots 0-3, L1 slots 4-7) ----
        float qa0 = fmaf(wx0, xsel, bb0), qb0 = 0.f;
        float qa1 = fmaf(wx1, xsel, bb1), qb1 = 0.f;
        float qa2 = fmaf(wx2, xsel, bb2), qb2 = 0.f;
        float qa3 = fmaf(wx3, xsel, bb3), qb3 = 0.f;
        if (s != 0) {                            // uniform: window start has h0 = 0
            FMA4(qa0, W0a, h0a) FMA4(qb0, W0b, h0b)
            FMA4(qa1, W1a, h0a) FMA4(qb1, W1b, h0b)
            FMA4(qa2, W2a, h0a) FMA4(qb2, W2b, h0b)
            FMA4(qa3, W3a, h0a) FMA4(qb3, W3b, h0b)
        }
        float qa4 = bb4, qb4 = 0.f;
        float qa5 = bb5, qb5 = 0.f;
        float qa6 = bb6, qb6 = 0.f;
        float qa7 = bb7, qb7 = 0.f;
        FMA4(qa4, U4a, h0a) FMA4(qb4, U4b, h0b)
        FMA4(qa5, U5a, h0a) FMA4(qb5, U5b, h0b)
        FMA4(qa6, U6a, h0a) FMA4(qb6, U6b, h0b)
        FMA4(qa7, U7a, h0a) FMA4(qb7, U7b, h0b)
        if (!(s == 1 || t == 0)) {               // uniform: L1 window start has h1 = 0
            f4 h1a = H1p[0], h1b = H1p[1];
            FMA4(qa4, V4a, h1a) FMA4(qb4, V4b, h1b)
            FMA4(qa5, V5a, h1a) FMA4(qb5, V5b, h1b)
            FMA4(qa6, V6a, h1a) FMA4(qb6, V6b, h1b)
            FMA4(qa7, V7a, h1a) FMA4(qb7, V7b, h1b)
        }

        // ---- select-free DPP butterfly (slot m holds value m^q2 at every stage) ----
        float Q0 = qa0 + qb0, Q1 = qa1 + qb1, Q2 = qa2 + qb2, Q3 = qa3 + qb3;
        float Q4 = qa4 + qb4, Q5 = qa5 + qb5, Q6 = qa6 + qb6, Q7 = qa7 + qb7;
        {   // stage d=1: Q[m] += dpp_xor1(Q[m^1])   (all 8 slots live)
            float t0 = dppf<XOR1>(Q1), t1 = dppf<XOR1>(Q0), t2 = dppf<XOR1>(Q3), t3 = dppf<XOR1>(Q2);
            float t4 = dppf<XOR1>(Q5), t5 = dppf<XOR1>(Q4), t6 = dppf<XOR1>(Q7), t7 = dppf<XOR1>(Q6);
            Q0 += t0; Q1 += t1; Q2 += t2; Q3 += t3; Q4 += t4; Q5 += t5; Q6 += t6; Q7 += t7;
        }
        {   // stage d=2: keep slots {0,3,4,7}
            float u0 = dppf<XOR2>(Q2), u3 = dppf<XOR2>(Q1), u4 = dppf<XOR2>(Q6), u7 = dppf<XOR2>(Q5);
            Q0 += u0; Q3 += u3; Q4 += u4; Q7 += u7;
        }
        {   // stage d=7 (mirror): keep slots {0,4}; sources slot m^3
            float m0 = dppf<MIR7>(Q3), m4 = dppf<MIR7>(Q7);
            Q0 += m0; Q4 += m4;
        }
        // now: Q0 = L0 gate (q2) full sum, Q4 = L1 gate (q2) full sum — in every lane

        // ---- one activation per lane, then quad-broadcast gates ----
        const float y = lolane ? Q0 : Q4;
        const float a = fmaf(fs2, __builtin_amdgcn_rcpf(1.f + __expf(kae * y)), fs3);
        const float A_i = dppf<BC0>(a);
        const float A_f = dppf<BC1>(a);
        const float A_g = dppf<BC2>(a);
        const float A_o = dppf<BC3>(a);

        // ---- cell update (quad0 = L0, quad1 = L1; same code) ----
        const bool rst = lolane ? (s == 0) : (s == 1);   // t==0 L1 garbage flushed at t==1
        const bool upd = lolane ? doL0 : true;
        const float ig  = A_i * A_g;
        const float ccn = rst ? ig : fmaf(A_f, cc, ig);
        cc = upd ? ccn : cc;
        const float th = tanh_f(cc);
        const float hnew = A_o * th;
        hv = upd ? hnew : hv;

        if (doL0 && idx == 0) X0[wb][j] = hnew;   // layer0 h
        if (idx == 4)         X1[wb][j] = hnew;   // layer1 h

        // ---- epilogue for window w1 = t/8 - 1 (h1(w1,7) landed in X1[0] last phase) ----
        if ((s == 1) && (t > 8) && (tid < 128)) {
            const int w1 = (t >> 3) - 1;
            const int l  = tid & 63, wv = tid >> 6;
            const float hval = X1[0][l];
            float p = wl * hval;
#pragma unroll
            for (int off = 32; off > 0; off >>= 1) p += __shfl_down(p, off);
            if (l == 0) {
                const float prev = (w1 == 0) ? trajS[7*4 + 2 + wv] : outr[(w1 - 1) & 7][wv];
                const float o = prev + p + (wv ? bl1 : bl0);
                outr[w1 & 7][wv] = o;
                out[((size_t)row * NW + w1) * 2 + wv] = o;
            }
        }
        __syncthreads();                 // the ONE barrier per phase
    }

    // ---- final epilogue: window NW-1 (h1 in X1[0]) ----
    if (tid < 128) {
        const int l = tid & 63, wv = tid >> 6;
        const float hval = X1[0][l];
        float p = wl * hval;
#pragma unroll
        for (int off = 32; off > 0; off >>= 1) p += __shfl_down(p, off);
        if (l == 0) {
            const float prev = outr[(NW - 2) & 7][wv];
            const float o = prev + p + (wv ? bl1 : bl0);
            out[((size_t)row * NW + (NW - 1)) * 2 + wv] = o;
        }
    }

    // ---- final hidden/cell state (cc/hv are layer-resident per quad) ----
    {
        float* hn = out + (size_t)NB * NW * 2;
        float* cn = hn + 2 * NB * 64;
        if (idx == 0) {                       // quad0 owns layer0 state
            hn[(0 * NB + row) * 64 + j] = hv;
            cn[(0 * NB + row) * 64 + j] = cc;
        }
        if (idx == 4) {                       // quad1 owns layer1 state
            hn[(1 * NB + row) * 64 + j] = hv;
            cn[(1 * NB + row) * 64 + j] = cc;
        }
    }
}

extern "C" void kernel_launch(void* const* d_in, const int* in_sizes, int n_in,
                              void* d_out, int out_size, void* d_ws, size_t ws_size,
                              hipStream_t stream) {
    const float* traj = (const float*)d_in[0];
    const float* Wih0 = (const float*)d_in[1];
    const float* Whh0 = (const float*)d_in[2];
    const float* bih0 = (const float*)d_in[3];
    const float* bhh0 = (const float*)d_in[4];
    const float* Wih1 = (const float*)d_in[5];
    const float* Whh1 = (const float*)d_in[6];
    const float* bih1 = (const float*)d_in[7];
    const float* bhh1 = (const float*)d_in[8];
    const float* Wlin = (const float*)d_in[9];
    const float* blin = (const float*)d_in[10];
    float* out = (float*)d_out;

    or_lstm_dpp<<<dim3(NB), dim3(512), 0, stream>>>(
        traj, Wih0, Whh0, bih0, bhh0, Wih1, Whh1, bih1, bhh1, Wlin, blin, out);
}

// Round 4
// 1261.476 us; speedup vs baseline: 1.5732x; 1.1226x over previous
//
#include <hip/hip_runtime.h>
#include <math.h>

typedef float4 f4;
#define NW 248
#define NB 64
#define NPHASE (NW + 7)   // p = 0..254; phase p runs step s=(p-c)&7 of window w=p-s in slot c

__device__ __forceinline__ float tanh_f(float x) { return 2.0f * __builtin_amdgcn_rcpf(1.0f + __expf(-2.0f * x)) - 1.0f; }

// Single-op cross-lane via DPP (no LDS pipe).
template<int CTRL>
__device__ __forceinline__ float dppf(float v) {
    return __int_as_float(__builtin_amdgcn_update_dpp(0, __float_as_int(v), CTRL, 0xF, 0xF, true));
}
#define XOR1 0xB1   // quad_perm [1,0,3,2]
#define XOR2 0x4E   // quad_perm [2,3,0,1]
#define MIR7 0x141  // ROW_HALF_MIRROR: lane i -> 7-i within 8 (== xor 7)
#define BC0  0x00
#define BC1  0x55
#define BC2  0xAA
#define BC3  0xFF

// Opacity launder: keep weight registers pinned in VGPRs.
#define OPQ1(X) asm volatile("" : "+v"(X));
#define OPQ4(V) OPQ1(V.x) OPQ1(V.y) OPQ1(V.z) OPQ1(V.w)

#define FMA4(acc,W,H) { acc=fmaf((W).x,(H).x,acc); acc=fmaf((W).y,(H).y,acc); \
                        acc=fmaf((W).z,(H).z,acc); acc=fmaf((W).w,(H).w,acc); }

// Butterfly (verified round-3 invariant: reg m holds value (m&3)^q2, half bit2(m)) +
// unified activation + cell update. Uses Q0..Q7, lolane, fs2, fs3, kae from scope.
#define TAIL8(CC, SA, SB, VA, VB, HN)                                                     \
    {                                                                                     \
        float r0=dppf<XOR1>(Q1), r1=dppf<XOR1>(Q0), r2=dppf<XOR1>(Q3), r3=dppf<XOR1>(Q2); \
        float r4=dppf<XOR1>(Q5), r5=dppf<XOR1>(Q4), r6=dppf<XOR1>(Q7), r7=dppf<XOR1>(Q6); \
        Q0+=r0; Q1+=r1; Q2+=r2; Q3+=r3; Q4+=r4; Q5+=r5; Q6+=r6; Q7+=r7;                   \
        float u0=dppf<XOR2>(Q2), u3=dppf<XOR2>(Q1), u4=dppf<XOR2>(Q6), u7=dppf<XOR2>(Q5); \
        Q0+=u0; Q3+=u3; Q4+=u4; Q7+=u7;                                                   \
        float m0=dppf<MIR7>(Q3), m4=dppf<MIR7>(Q7);                                       \
        Q0+=m0; Q4+=m4;                                                                   \
        const float yv = lolane ? Q0 : Q4;                                                \
        const float av = fmaf(fs2, __builtin_amdgcn_rcpf(1.f + __expf(kae*yv)), fs3);     \
        const float gi = dppf<BC0>(av);                                                   \
        const float gf = dppf<BC1>(av);                                                   \
        const float gg = dppf<BC2>(av);                                                   \
        const float go = dppf<BC3>(av);                                                   \
        const bool rst = lolane ? ((SA)==0) : ((SB)==0);                                  \
        const bool upd = lolane ? (VA) : (VB);                                            \
        const float igv = gi * gg;                                                        \
        const float ccn = rst ? igv : fmaf(gf, CC, igv);                                  \
        CC = upd ? ccn : CC;                                                              \
        HN = go * tanh_f(CC);                                                             \
    }

__device__ __forceinline__ float xsel4(float x0, float x1, float x2, float x3, int q2) {
    return (q2 & 2) ? ((q2 & 1) ? x3 : x2) : ((q2 & 1) ? x1 : x0);
}

// General (prologue) x-sourcing — verbatim window/step logic from the verified kernel.
__device__ __forceinline__ float xload(const float* trajS, const float (*outr)[2],
                                       int w, int s, int q2) {
    float x0, x1, x2, x3;
    if (w == 0) {
        x0 = trajS[s*4+0]; x1 = trajS[s*4+1]; x2 = trajS[s*4+2]; x3 = trajS[s*4+3];
    } else if (w < 8) {
        if (s < 8 - w) {
            const int tt = w + s;
            x0 = trajS[tt*4+0]; x1 = trajS[tt*4+1]; x2 = trajS[tt*4+2]; x3 = trajS[tt*4+3];
        } else {
            const int tc = 2*w + s - 1;
            const int jo2 = (w + s - 8) & 7;
            x0 = trajS[tc*4+0]; x1 = trajS[tc*4+1];
            x2 = outr[jo2][0];  x3 = outr[jo2][1];
        }
    } else {
        const int tc = w + s;
        const int jo2 = (w + s) & 7;
        x0 = trajS[tc*4+0]; x1 = trajS[tc*4+1];
        x2 = outr[jo2][0];  x3 = outr[jo2][1];
    }
    return xsel4(x0, x1, x2, x3, q2);
}

__global__ __launch_bounds__(512)
void or_lstm_wpar(const float* __restrict__ traj,
                  const float* __restrict__ Wih0, const float* __restrict__ Whh0,
                  const float* __restrict__ bih0, const float* __restrict__ bhh0,
                  const float* __restrict__ Wih1, const float* __restrict__ Whh1,
                  const float* __restrict__ bih1, const float* __restrict__ bhh1,
                  const float* __restrict__ Wlin, const float* __restrict__ blin,
                  float* __restrict__ out)
{
    const int row = blockIdx.x;
    const int tid = threadIdx.x;      // = j*8 + idx
    const int j   = tid >> 3;         // h index 0..63
    const int idx = tid & 7;          // K-slice 0..7 (8 floats each)
    const int q2  = idx & 3;

    __shared__ __align__(16) float trajS[256 * 4];
    __shared__ __align__(16) float X0[2][8][64];   // [parity][slot][j] layer-0 h
    __shared__ __align__(16) float X1[2][8][64];   // [parity][slot][j] layer-1 h
    __shared__ float outr[8][2];                   // ring of last 8 predictions

    if (tid < 256)
        ((f4*)trajS)[tid] = ((const f4*)(traj + (size_t)row * 256 * 4))[tid];
    ((float*)X0)[tid] = 0.f; ((float*)X0)[tid + 512] = 0.f;
    ((float*)X1)[tid] = 0.f; ((float*)X1)[tid + 512] = 0.f;

    // ---- gate-permuted weight slices: reg m holds gate v=m^q2 (shared by paired windows) ----
    const int jo = j * 64 + idx * 8;
    const int v0 = q2, v1 = 1 ^ q2, v2 = 2 ^ q2, v3 = 3 ^ q2;
    f4 W0a = *(const f4*)(Whh0 + v0*4096 + jo), W0b = *(const f4*)(Whh0 + v0*4096 + jo + 4);
    f4 W1a = *(const f4*)(Whh0 + v1*4096 + jo), W1b = *(const f4*)(Whh0 + v1*4096 + jo + 4);
    f4 W2a = *(const f4*)(Whh0 + v2*4096 + jo), W2b = *(const f4*)(Whh0 + v2*4096 + jo + 4);
    f4 W3a = *(const f4*)(Whh0 + v3*4096 + jo), W3b = *(const f4*)(Whh0 + v3*4096 + jo + 4);
    f4 U0a = *(const f4*)(Wih1 + v0*4096 + jo), U0b = *(const f4*)(Wih1 + v0*4096 + jo + 4);
    f4 U1a = *(const f4*)(Wih1 + v1*4096 + jo), U1b = *(const f4*)(Wih1 + v1*4096 + jo + 4);
    f4 U2a = *(const f4*)(Wih1 + v2*4096 + jo), U2b = *(const f4*)(Wih1 + v2*4096 + jo + 4);
    f4 U3a = *(const f4*)(Wih1 + v3*4096 + jo), U3b = *(const f4*)(Wih1 + v3*4096 + jo + 4);
    f4 V0a = *(const f4*)(Whh1 + v0*4096 + jo), V0b = *(const f4*)(Whh1 + v0*4096 + jo + 4);
    f4 V1a = *(const f4*)(Whh1 + v1*4096 + jo), V1b = *(const f4*)(Whh1 + v1*4096 + jo + 4);
    f4 V2a = *(const f4*)(Whh1 + v2*4096 + jo), V2b = *(const f4*)(Whh1 + v2*4096 + jo + 4);
    f4 V3a = *(const f4*)(Whh1 + v3*4096 + jo), V3b = *(const f4*)(Whh1 + v3*4096 + jo + 4);
    OPQ4(W0a) OPQ4(W0b) OPQ4(W1a) OPQ4(W1b) OPQ4(W2a) OPQ4(W2b) OPQ4(W3a) OPQ4(W3b)
    OPQ4(U0a) OPQ4(U0b) OPQ4(U1a) OPQ4(U1b) OPQ4(U2a) OPQ4(U2b) OPQ4(U3a) OPQ4(U3b)
    OPQ4(V0a) OPQ4(V0b) OPQ4(V1a) OPQ4(V1b) OPQ4(V2a) OPQ4(V2b) OPQ4(V3a) OPQ4(V3b)

    float wx0 = (idx < 4) ? Wih0[v0*256 + j*4 + q2] : 0.f;
    float wx1 = (idx < 4) ? Wih0[v1*256 + j*4 + q2] : 0.f;
    float wx2 = (idx < 4) ? Wih0[v2*256 + j*4 + q2] : 0.f;
    float wx3 = (idx < 4) ? Wih0[v3*256 + j*4 + q2] : 0.f;
    float bb00 = (idx == 0) ? (bih0[0*64+j] + bhh0[0*64+j]) : 0.f;
    float bb01 = (idx == 0) ? (bih0[1*64+j] + bhh0[1*64+j]) : 0.f;
    float bb02 = (idx == 0) ? (bih0[2*64+j] + bhh0[2*64+j]) : 0.f;
    float bb03 = (idx == 0) ? (bih0[3*64+j] + bhh0[3*64+j]) : 0.f;
    float bb10 = (idx == 0) ? (bih1[0*64+j] + bhh1[0*64+j]) : 0.f;
    float bb11 = (idx == 0) ? (bih1[1*64+j] + bhh1[1*64+j]) : 0.f;
    float bb12 = (idx == 0) ? (bih1[2*64+j] + bhh1[2*64+j]) : 0.f;
    float bb13 = (idx == 0) ? (bih1[3*64+j] + bhh1[3*64+j]) : 0.f;
    OPQ1(wx0) OPQ1(wx1) OPQ1(wx2) OPQ1(wx3)
    OPQ1(bb00) OPQ1(bb01) OPQ1(bb02) OPQ1(bb03)
    OPQ1(bb10) OPQ1(bb11) OPQ1(bb12) OPQ1(bb13)

    const float kae = (q2 == 2) ? -2.f : -1.f;
    const float fs2 = (q2 == 2) ?  2.f :  1.f;
    const float fs3 = (q2 == 2) ? -1.f :  0.f;

    float wl = 0.f;
    if (tid < 128) wl = Wlin[tid];
    const float bl0 = blin[0], bl1 = blin[1];

    const bool lolane = (idx < 4);    // quad0 owns even slot (A), quad1 odd slot (B) of each pair
    float cc0[4] = {0.f, 0.f, 0.f, 0.f};   // L0 cell per pair (A in quad0, B in quad1)
    float cc1[4] = {0.f, 0.f, 0.f, 0.f};   // L1 cell per pair

    __syncthreads();

    // Window-parallel pipeline: 8 windows in flight, staggered 1 step apart.
    for (int p = 0; p < NPHASE; ++p) {
        const int par = p & 1;
        float* X0r = &X0[par ^ 1][0][idx * 8];   // L0 input h0(s-1)
        float* X0n = &X0[par    ][0][idx * 8];   // L1 input h0(s)   (after bar1)
        float* X1r = &X1[par ^ 1][0][idx * 8];   // L1 input h1(s-1)
        float* X0w = &X0[par][0][j];
        float* X1w = &X1[par][0][j];

        int  sS[8]; bool vS[8];
        #pragma unroll
        for (int c = 0; c < 8; ++c) {
            const int s = (p - c) & 7;
            const int w = p - s;
            sS[c] = s;
            vS[c] = ((unsigned)w < (unsigned)NW);
        }

        // ---- x input (all in-flight windows read trajectory row p in steady state) ----
        float xs[8];
        if (p >= 15) {
            const float xc = xsel4(trajS[p*4+0], trajS[p*4+1],
                                   outr[p & 7][0], outr[p & 7][1], q2);
            #pragma unroll
            for (int c = 0; c < 8; ++c) xs[c] = xc;
        } else {
            #pragma unroll
            for (int c = 0; c < 8; ++c)
                xs[c] = vS[c] ? xload(trajS, outr, p - sS[c], sS[c], q2) : 0.f;
        }

        // ======== half 1: layer 0, all 8 slots (4 pairs) ========
        #pragma unroll
        for (int P = 0; P < 4; ++P) {
            const int cA = 2*P, cB = 2*P + 1;
            const int sA = sS[cA], sB = sS[cB];
            const bool vA = vS[cA], vB = vS[cB];
            float qa0 = fmaf(wx0, xs[cA], bb00), qb0 = 0.f;
            float qa1 = fmaf(wx1, xs[cA], bb01), qb1 = 0.f;
            float qa2 = fmaf(wx2, xs[cA], bb02), qb2 = 0.f;
            float qa3 = fmaf(wx3, xs[cA], bb03), qb3 = 0.f;
            float qa4 = fmaf(wx0, xs[cB], bb00), qb4 = 0.f;
            float qa5 = fmaf(wx1, xs[cB], bb01), qb5 = 0.f;
            float qa6 = fmaf(wx2, xs[cB], bb02), qb6 = 0.f;
            float qa7 = fmaf(wx3, xs[cB], bb03), qb7 = 0.f;
            if (sA != 0) {
                const f4 ha = *(const f4*)(X0r + cA*64), hb = *(const f4*)(X0r + cA*64 + 4);
                FMA4(qa0, W0a, ha) FMA4(qb0, W0b, hb)
                FMA4(qa1, W1a, ha) FMA4(qb1, W1b, hb)
                FMA4(qa2, W2a, ha) FMA4(qb2, W2b, hb)
                FMA4(qa3, W3a, ha) FMA4(qb3, W3b, hb)
            }
            if (sB != 0) {
                const f4 ha = *(const f4*)(X0r + cB*64), hb = *(const f4*)(X0r + cB*64 + 4);
                FMA4(qa4, W0a, ha) FMA4(qb4, W0b, hb)
                FMA4(qa5, W1a, ha) FMA4(qb5, W1b, hb)
                FMA4(qa6, W2a, ha) FMA4(qb6, W2b, hb)
                FMA4(qa7, W3a, ha) FMA4(qb7, W3b, hb)
            }
            float Q0 = qa0+qb0, Q1 = qa1+qb1, Q2 = qa2+qb2, Q3 = qa3+qb3;
            float Q4 = qa4+qb4, Q5 = qa5+qb5, Q6 = qa6+qb6, Q7 = qa7+qb7;
            float hn0;
            TAIL8(cc0[P], sA, sB, vA, vB, hn0)
            if (vA && idx == 0) X0w[cA*64] = hn0;
            if (vB && idx == 4) X0w[cB*64] = hn0;
        }
        __syncthreads();                 // bar1: h0(s) visible

        // ======== half 2: layer 1, all 8 slots ========
        #pragma unroll
        for (int P = 0; P < 4; ++P) {
            const int cA = 2*P, cB = 2*P + 1;
            const int sA = sS[cA], sB = sS[cB];
            const bool vA = vS[cA], vB = vS[cB];
            float qa0 = bb10, qb0 = 0.f;
            float qa1 = bb11, qb1 = 0.f;
            float qa2 = bb12, qb2 = 0.f;
            float qa3 = bb13, qb3 = 0.f;
            float qa4 = bb10, qb4 = 0.f;
            float qa5 = bb11, qb5 = 0.f;
            float qa6 = bb12, qb6 = 0.f;
            float qa7 = bb13, qb7 = 0.f;
            {
                const f4 ga = *(const f4*)(X0n + cA*64), gb = *(const f4*)(X0n + cA*64 + 4);
                FMA4(qa0, U0a, ga) FMA4(qb0, U0b, gb)
                FMA4(qa1, U1a, ga) FMA4(qb1, U1b, gb)
                FMA4(qa2, U2a, ga) FMA4(qb2, U2b, gb)
                FMA4(qa3, U3a, ga) FMA4(qb3, U3b, gb)
                const f4 gc = *(const f4*)(X0n + cB*64), gd = *(const f4*)(X0n + cB*64 + 4);
                FMA4(qa4, U0a, gc) FMA4(qb4, U0b, gd)
                FMA4(qa5, U1a, gc) FMA4(qb5, U1b, gd)
                FMA4(qa6, U2a, gc) FMA4(qb6, U2b, gd)
                FMA4(qa7, U3a, gc) FMA4(qb7, U3b, gd)
            }
            if (sA != 0) {
                const f4 ea = *(const f4*)(X1r + cA*64), eb = *(const f4*)(X1r + cA*64 + 4);
                FMA4(qa0, V0a, ea) FMA4(qb0, V0b, eb)
                FMA4(qa1, V1a, ea) FMA4(qb1, V1b, eb)
                FMA4(qa2, V2a, ea) FMA4(qb2, V2b, eb)
                FMA4(qa3, V3a, ea) FMA4(qb3, V3b, eb)
            }
            if (sB != 0) {
                const f4 ea = *(const f4*)(X1r + cB*64), eb = *(const f4*)(X1r + cB*64 + 4);
                FMA4(qa4, V0a, ea) FMA4(qb4, V0b, eb)
                FMA4(qa5, V1a, ea) FMA4(qb5, V1b, eb)
                FMA4(qa6, V2a, ea) FMA4(qb6, V2b, eb)
                FMA4(qa7, V3a, ea) FMA4(qb7, V3b, eb)
            }
            float Q0 = qa0+qb0, Q1 = qa1+qb1, Q2 = qa2+qb2, Q3 = qa3+qb3;
            float Q4 = qa4+qb4, Q5 = qa5+qb5, Q6 = qa6+qb6, Q7 = qa7+qb7;
            float hn1;
            TAIL8(cc1[P], sA, sB, vA, vB, hn1)
            if (vA && idx == 0) X1w[cA*64] = hn1;
            if (vB && idx == 4) X1w[cB*64] = hn1;
        }
        __syncthreads();                 // bar2: h1(s) visible (incl. finishing window)

        // ======== epilogue third: window w1 = p-7 just finished (slot (p+1)&7) ========
        if (p >= 7 && tid < 128) {
            const int w1 = p - 7;
            const int l = tid & 63, wv = tid >> 6;
            const float hval = X1[par][(p + 1) & 7][l];
            float pp = wl * hval;
            #pragma unroll
            for (int off = 32; off > 0; off >>= 1) pp += __shfl_down(pp, off);
            if (l == 0) {
                const float prev = (w1 == 0) ? trajS[7*4 + 2 + wv] : outr[(w1 - 1) & 7][wv];
                const float o = prev + pp + (wv ? bl1 : bl0);
                outr[w1 & 7][wv] = o;
                out[((size_t)row * NW + w1) * 2 + wv] = o;
            }
        }
        __syncthreads();                 // bar3: outr visible to next phase's readers
    }

    // ---- final hidden/cell state: window NW-1 lives in slot 7 (pair 3, B -> quad1) ----
    if (idx == 4) {
        float* hn = out + (size_t)NB * NW * 2;
        float* cn = hn + 2 * NB * 64;
        hn[(0 * NB + row) * 64 + j] = X0[0][7][j];   // p=254 wrote parity 0
        hn[(1 * NB + row) * 64 + j] = X1[0][7][j];
        cn[(0 * NB + row) * 64 + j] = cc0[3];
        cn[(1 * NB + row) * 64 + j] = cc1[3];
    }
}

extern "C" void kernel_launch(void* const* d_in, const int* in_sizes, int n_in,
                              void* d_out, int out_size, void* d_ws, size_t ws_size,
                              hipStream_t stream) {
    const float* traj = (const float*)d_in[0];
    const float* Wih0 = (const float*)d_in[1];
    const float* Whh0 = (const float*)d_in[2];
    const float* bih0 = (const float*)d_in[3];
    const float* bhh0 = (const float*)d_in[4];
    const float* Wih1 = (const float*)d_in[5];
    const float* Whh1 = (const float*)d_in[6];
    const float* bih1 = (const float*)d_in[7];
    const float* bhh1 = (const float*)d_in[8];
    const float* Wlin = (const float*)d_in[9];
    const float* blin = (const float*)d_in[10];
    float* out = (float*)d_out;

    or_lstm_wpar<<<dim3(NB), dim3(512), 0, stream>>>(
        traj, Wih0, Whh0, bih0, bhh0, Wih1, Whh1, bih1, bhh1, Wlin, blin, out);
}